// Round 15
// baseline (6495.657 us; speedup 1.0000x reference)
//
#include <hip/hip_runtime.h>

// LSTM T=16384, B=32, H=96. 32 blocks x 384 thr. R14 = 6285us. R13->R14
// showed instr-trims now under-deliver -> serial chain co-limits. This round
// shortens the chain: (1) weights/bias/x pre-scaled by -log2e (-2log2e for
// g-gate rows) so act = rcp(1+exp2(pre)) with no arg mul; (2) slot-0 dot
// chain seeded with fmaf(xv,wih,bias) BEFORE the ds_read returns (x-term off
// the post-reduce path); (3) c carried pre-scaled (c_s = -2log2e*c; lane 2
// broadcasts k*g via folded fma constants) so tanh(c) = rcp(1+exp2(c_s));
// (4) dot chains split 12 -> 6+6 (+4 adds, -24 cyc dependent latency).
// Everything else per R14: XOR-indexed weights (butterfly with no selects),
// slot-shifted 513-row f16 h history, float4 x broadcast per 4 steps, ds
// offset immediates, one barrier/step, bulk fc flush every 512 steps.

constexpr int HH   = 96;
constexpr int BB   = 32;
constexpr int TT   = 16384;
constexpr int TH   = 384;   // 6 waves
constexpr int NS   = 512;   // h history window
constexpr int ROWP = 104;   // halves per hist row: 208 B, 16B-aligned

typedef _Float16 f16x2 __attribute__((ext_vector_type(2)));

__device__ __forceinline__ float dot2_f16(f16x2 a, f16x2 b, float c) {
    float d;
    int ai = __builtin_bit_cast(int, a);
    int bi = __builtin_bit_cast(int, b);
    asm("v_dot2_f32_f16 %0, %1, %2, %3" : "=v"(d) : "v"(ai), "v"(bi), "v"(c));
    return d;
}

// a + (b cross-laned by CTRL)
template <int CTRL>
__device__ __forceinline__ float dpp_add2(float a, float b) {
    int r = __builtin_amdgcn_mov_dpp(__builtin_bit_cast(int, b), CTRL, 0xF, 0xF, true);
    return a + __builtin_bit_cast(float, r);
}
template <int CTRL>
__device__ __forceinline__ float dpp_bcast(float v) {
    int r = __builtin_amdgcn_mov_dpp(__builtin_bit_cast(int, v), CTRL, 0xF, 0xF, true);
    return __builtin_bit_cast(float, r);
}
constexpr int DPP_XOR1 = 0xB1;  // quad_perm [1,0,3,2]
constexpr int DPP_XOR2 = 0x4E;  // quad_perm [2,3,0,1]
constexpr int DPP_B1   = 0x55;
constexpr int DPP_B2   = 0xAA;
constexpr int DPP_B3   = 0xFF;

#define LOG2E 1.44269504f

__attribute__((amdgpu_flat_work_group_size(TH, TH), amdgpu_waves_per_eu(1, 2)))
__global__ void lstm_kernel(const float* __restrict__ x,
                            const float* __restrict__ w_ih,
                            const float* __restrict__ w_hh,
                            const float* __restrict__ b_ih,
                            const float* __restrict__ b_hh,
                            const float* __restrict__ fc_w,
                            const float* __restrict__ fc_b,
                            float* __restrict__ out) {
    __shared__ __align__(16) _Float16 hist[(NS + 1) * ROWP];  // ~104 KB
    __shared__ __align__(16) float xs[NS];                    // 2 KB x window
    __shared__ float fcw_s[HH];

    const int tid = threadIdx.x;
    const int b   = blockIdx.x;
    const int j   = tid >> 2;    // cell 0..95
    const int s   = tid & 3;     // k-slice [24s,24s+24) halves; also "my gate"

    // XOR-indexed + pre-scaled weights: slot d holds gate (s^d)'s row slice,
    // scaled by -log2e (sigmoid gates) or -2log2e (g/tanh gate).
    f16x2 W[4][12];
#pragma unroll
    for (int d = 0; d < 4; ++d) {
        const int  g  = s ^ d;
        const float sc = (g == 2) ? (-2.0f * LOG2E) : (-LOG2E);
        const float* wr = w_hh + (g * HH + j) * HH + 24 * s;
#pragma unroll
        for (int m = 0; m < 12; ++m)
            W[d][m] = f16x2{(_Float16)(wr[2 * m] * sc), (_Float16)(wr[2 * m + 1] * sc)};
    }
#pragma unroll
    for (int d = 0; d < 4; ++d)
#pragma unroll
        for (int m = 0; m < 12; ++m) asm volatile("" : "+v"(W[d][m]));

    const float ks     = (s == 2) ? (-2.0f * LOG2E) : (-LOG2E);
    const float wih_s  = w_ih[s * HH + j] * ks;
    const float bias_s = (b_ih[s * HH + j] + b_hh[s * HH + j]) * ks;
    // act = fma(a_mul, r, a_add), r = rcp(1+exp2(pre)).
    // lanes 0,1,3 (sigmoid): act = r.  lane 2: act = k2*tanh = k2*(2r-1),
    // k2 = -2log2e (so the B2 broadcast is already k2*g for the scaled-c carry).
    const float k2    = -2.0f * LOG2E;
    const float a_mul = (s == 2) ? (2.0f * k2) : 1.0f;
    const float a_add = (s == 2) ? (-k2) : 0.0f;

    const float fcb = fc_b[0];
    float c = 0.0f;   // carried as c_s = -2log2e * c_true

    for (int i = tid; i < HH; i += TH) fcw_s[i] = fc_w[i];

    // Bulk fc projection for window [t0, t0+NS): h(t0+i) is in hist row i+1.
    auto flush = [&](int t0) {
        for (int i = tid; i < NS; i += TH) {
            const uint2* hr = (const uint2*)(hist + (i + 1) * ROWP);
            float a = 0.0f;
#pragma unroll
            for (int m = 0; m < 24; ++m) {
                uint2 u = hr[m];
                f16x2 p0 = __builtin_bit_cast(f16x2, u.x);
                f16x2 p1 = __builtin_bit_cast(f16x2, u.y);
                a = fmaf((float)p0.x, fcw_s[4 * m + 0], a);
                a = fmaf((float)p0.y, fcw_s[4 * m + 1], a);
                a = fmaf((float)p1.x, fcw_s[4 * m + 2], a);
                a = fmaf((float)p1.y, fcw_s[4 * m + 3], a);
            }
            out[(t0 + i) * BB + b] = a + fcb + xs[i];
        }
    };

    const _Float16* rd_p;  // h(t-1) slice base; advanced 4 rows at a time
    _Float16*       wr_p;  // h(t) cell slot base

    auto step = [&](float xv, const int ofs) {
        // x-seed computed before the LDS data is needed (independent of h).
        const float seed = fmaf(xv, wih_s, bias_s);
        const uint4* hrow = (const uint4*)(rd_p + ofs);
        uint4 u0 = hrow[0], u1 = hrow[1], u2 = hrow[2];
        f16x2 h2[12] = {
            __builtin_bit_cast(f16x2, u0.x), __builtin_bit_cast(f16x2, u0.y),
            __builtin_bit_cast(f16x2, u0.z), __builtin_bit_cast(f16x2, u0.w),
            __builtin_bit_cast(f16x2, u1.x), __builtin_bit_cast(f16x2, u1.y),
            __builtin_bit_cast(f16x2, u1.z), __builtin_bit_cast(f16x2, u1.w),
            __builtin_bit_cast(f16x2, u2.x), __builtin_bit_cast(f16x2, u2.y),
            __builtin_bit_cast(f16x2, u2.z), __builtin_bit_cast(f16x2, u2.w)};

        float acc[4];
#pragma unroll
        for (int d = 0; d < 4; ++d) {
            float e0 = (d == 0) ? seed : 0.0f;
            float e1 = 0.0f;
#pragma unroll
            for (int m = 0; m < 6; ++m)  e0 = dot2_f16(W[d][m], h2[m], e0);
#pragma unroll
            for (int m = 6; m < 12; ++m) e1 = dot2_f16(W[d][m], h2[m], e1);
            acc[d] = e0 + e1;
        }
        // XOR butterfly: lane s ends with gate-s's full (pre-scaled) sum.
        const float b0 = dpp_add2<DPP_XOR1>(acc[0], acc[1]);
        const float b1 = dpp_add2<DPP_XOR1>(acc[2], acc[3]);
        const float pre = dpp_add2<DPP_XOR2>(b0, b1);

        const float r   = __builtin_amdgcn_rcpf(1.0f + __builtin_amdgcn_exp2f(pre));
        const float act = fmaf(a_mul, r, a_add);

        const float fv = dpp_bcast<DPP_B1>(act);   // f (sigmoid)
        const float gk = dpp_bcast<DPP_B2>(act);   // k2 * g
        const float ov = dpp_bcast<DPP_B3>(act);   // o (sigmoid)
        c = fmaf(fv, c, act * gk);                 // c_s update (lane0: act=i)
        const float r2 = __builtin_amdgcn_rcpf(1.0f + __builtin_amdgcn_exp2f(c));
        const float h  = ov * fmaf(2.0f, r2, -1.0f);   // o * tanh(c_true)
        if (s == 0) *(wr_p + ofs) = (_Float16)h;
        __syncthreads();
    };

    for (int w = 0; w < TT / NS; ++w) {
        const int t0 = w * NS;
        if (w == 0) {
            if (tid < 48) ((uint32_t*)hist)[tid] = 0u;  // row 0 = h(-1) = 0
        } else {
            flush(t0 - NS);                              // old xs + rows 1..512
            if (tid < 48)                                // row 512 -> row 0
                ((uint32_t*)hist)[tid] = ((const uint32_t*)(hist + NS * ROWP))[tid];
        }
        __syncthreads();
        for (int i = tid; i < NS; i += TH) xs[i] = x[(t0 + i) * BB + b];
        __syncthreads();

        rd_p = hist + 24 * s;
        wr_p = hist + ROWP + j;
        for (int tt = 0; tt < NS; tt += 4) {
            const float4 xq = *(const float4*)(xs + tt);  // broadcast
            step(xq.x, 0 * ROWP);
            step(xq.y, 1 * ROWP);
            step(xq.z, 2 * ROWP);
            step(xq.w, 3 * ROWP);
            rd_p += 4 * ROWP;
            wr_p += 4 * ROWP;
        }
    }
    flush(TT - NS);   // last window (loop ended with a barrier)
}

extern "C" void kernel_launch(void* const* d_in, const int* in_sizes, int n_in,
                              void* d_out, int out_size, void* d_ws, size_t ws_size,
                              hipStream_t stream) {
    const float* x    = (const float*)d_in[0];
    const float* w_ih = (const float*)d_in[1];
    const float* w_hh = (const float*)d_in[2];
    const float* b_ih = (const float*)d_in[3];
    const float* b_hh = (const float*)d_in[4];
    const float* fc_w = (const float*)d_in[5];
    const float* fc_b = (const float*)d_in[6];
    float* out = (float*)d_out;

    lstm_kernel<<<dim3(BB), dim3(TH), 0, stream>>>(x, w_ih, w_hh, b_ih, b_hh,
                                                   fc_w, fc_b, out);
}

// Round 16
// 6304.650 us; speedup vs baseline: 1.0303x; 1.0303x over previous
//
#include <hip/hip_runtime.h>

// LSTM T=16384, B=32, H=96. 32 blocks x 384 thr. Best = R14 (6285us).
// R15 bundle regressed (chain-split +4 instr cost 2% -> still issue-sensitive
// at ~1.8ns/instr; pre-scaled f16 weights doubled absmax) -> reverted.
// This round = EXACT R14 plus only the surgical wins:
//  (1) x-seed fmaf(xv,wih,bias) starts the acc[0] dot chain (computed before
//      the ds_read returns; removes the post-butterfly add from the path);
//  (2) inner loop unrolled 8 with ds offset immediates (loop bookkeeping /2);
//  (3) both x float4s for the 8 steps read up front.
// Structure: thread (j=tid>>2, s=tid&3), XOR-indexed weights (slot d = gate
// s^d) -> 3-op butterfly leaves lane s with gate-s's full sum, no selects;
// v_dot2_f32_f16 dots (48 weight VGPRs); exp2-folded activations; quad bcast
// f,g,o; redundant c/h per quad; slot-shifted 513-row f16 h history (no wrap
// logic inside the window); one barrier/step; bulk fc flush every 512 steps.

constexpr int HH   = 96;
constexpr int BB   = 32;
constexpr int TT   = 16384;
constexpr int TH   = 384;   // 6 waves
constexpr int NS   = 512;   // h history window
constexpr int ROWP = 104;   // halves per hist row: 208 B, 16B-aligned

typedef _Float16 f16x2 __attribute__((ext_vector_type(2)));

__device__ __forceinline__ float dot2_f16(f16x2 a, f16x2 b, float c) {
    float d;
    int ai = __builtin_bit_cast(int, a);
    int bi = __builtin_bit_cast(int, b);
    asm("v_dot2_f32_f16 %0, %1, %2, %3" : "=v"(d) : "v"(ai), "v"(bi), "v"(c));
    return d;
}

// a + (b cross-laned by CTRL)
template <int CTRL>
__device__ __forceinline__ float dpp_add2(float a, float b) {
    int r = __builtin_amdgcn_mov_dpp(__builtin_bit_cast(int, b), CTRL, 0xF, 0xF, true);
    return a + __builtin_bit_cast(float, r);
}
template <int CTRL>
__device__ __forceinline__ float dpp_bcast(float v) {
    int r = __builtin_amdgcn_mov_dpp(__builtin_bit_cast(int, v), CTRL, 0xF, 0xF, true);
    return __builtin_bit_cast(float, r);
}
constexpr int DPP_XOR1 = 0xB1;  // quad_perm [1,0,3,2]
constexpr int DPP_XOR2 = 0x4E;  // quad_perm [2,3,0,1]
constexpr int DPP_B1   = 0x55;
constexpr int DPP_B2   = 0xAA;
constexpr int DPP_B3   = 0xFF;

#define LOG2E 1.44269504f

__attribute__((amdgpu_flat_work_group_size(TH, TH), amdgpu_waves_per_eu(1, 2)))
__global__ void lstm_kernel(const float* __restrict__ x,
                            const float* __restrict__ w_ih,
                            const float* __restrict__ w_hh,
                            const float* __restrict__ b_ih,
                            const float* __restrict__ b_hh,
                            const float* __restrict__ fc_w,
                            const float* __restrict__ fc_b,
                            float* __restrict__ out) {
    __shared__ __align__(16) _Float16 hist[(NS + 1) * ROWP];  // ~104 KB
    __shared__ __align__(16) float xs[NS];                    // 2 KB x window
    __shared__ float fcw_s[HH];

    const int tid = threadIdx.x;
    const int b   = blockIdx.x;
    const int j   = tid >> 2;    // cell 0..95
    const int s   = tid & 3;     // k-slice [24s,24s+24) halves; also "my gate"

    // XOR-indexed weight layout: slot d holds gate (s^d)'s row slice.
    f16x2 W[4][12];
#pragma unroll
    for (int d = 0; d < 4; ++d) {
        const float* wr = w_hh + (((s ^ d) * HH) + j) * HH + 24 * s;
#pragma unroll
        for (int m = 0; m < 12; ++m)
            W[d][m] = f16x2{(_Float16)wr[2 * m], (_Float16)wr[2 * m + 1]};
    }
#pragma unroll
    for (int d = 0; d < 4; ++d)
#pragma unroll
        for (int m = 0; m < 12; ++m) asm volatile("" : "+v"(W[d][m]));

    const float wih_s  = w_ih[s * HH + j];
    const float bias_s = b_ih[s * HH + j] + b_hh[s * HH + j];
    const float e_k   = (s == 2) ? (-2.0f * LOG2E) : (-LOG2E);
    const float a_mul = (s == 2) ? 2.0f : 1.0f;
    const float a_add = (s == 2) ? -1.0f : 0.0f;

    const float fcb = fc_b[0];
    float c = 0.0f;

    for (int i = tid; i < HH; i += TH) fcw_s[i] = fc_w[i];

    // Bulk fc projection for window [t0, t0+NS): h(t0+i) is in hist row i+1.
    auto flush = [&](int t0) {
        for (int i = tid; i < NS; i += TH) {
            const uint2* hr = (const uint2*)(hist + (i + 1) * ROWP);
            float a = 0.0f;
#pragma unroll
            for (int m = 0; m < 24; ++m) {
                uint2 u = hr[m];
                f16x2 p0 = __builtin_bit_cast(f16x2, u.x);
                f16x2 p1 = __builtin_bit_cast(f16x2, u.y);
                a = fmaf((float)p0.x, fcw_s[4 * m + 0], a);
                a = fmaf((float)p0.y, fcw_s[4 * m + 1], a);
                a = fmaf((float)p1.x, fcw_s[4 * m + 2], a);
                a = fmaf((float)p1.y, fcw_s[4 * m + 3], a);
            }
            out[(t0 + i) * BB + b] = a + fcb + xs[i];
        }
    };

    const _Float16* rd_p;  // h(t-1) slice base; advanced 8 rows at a time
    _Float16*       wr_p;  // h(t) cell slot base

    auto step = [&](float xv, const int ofs) {
        // x-seed: independent of h -> computed while the ds_read is in flight,
        // and it STARTS the acc[0] chain (no post-butterfly add).
        const float seed = fmaf(xv, wih_s, bias_s);
        const uint4* hrow = (const uint4*)(rd_p + ofs);
        uint4 u0 = hrow[0], u1 = hrow[1], u2 = hrow[2];
        f16x2 h2[12] = {
            __builtin_bit_cast(f16x2, u0.x), __builtin_bit_cast(f16x2, u0.y),
            __builtin_bit_cast(f16x2, u0.z), __builtin_bit_cast(f16x2, u0.w),
            __builtin_bit_cast(f16x2, u1.x), __builtin_bit_cast(f16x2, u1.y),
            __builtin_bit_cast(f16x2, u1.z), __builtin_bit_cast(f16x2, u1.w),
            __builtin_bit_cast(f16x2, u2.x), __builtin_bit_cast(f16x2, u2.y),
            __builtin_bit_cast(f16x2, u2.z), __builtin_bit_cast(f16x2, u2.w)};

        float acc[4];
#pragma unroll
        for (int d = 0; d < 4; ++d) {
            float e = (d == 0) ? seed : 0.0f;
#pragma unroll
            for (int m = 0; m < 12; ++m) e = dot2_f16(W[d][m], h2[m], e);
            acc[d] = e;
        }
        // XOR butterfly: lane s ends with gate-s's full sum (seed counted
        // exactly once: only lane s's own slot-0 carries it into gate s).
        const float b0  = dpp_add2<DPP_XOR1>(acc[0], acc[1]);
        const float b1  = dpp_add2<DPP_XOR1>(acc[2], acc[3]);
        const float pre = dpp_add2<DPP_XOR2>(b0, b1);

        const float act =
            fmaf(__builtin_amdgcn_rcpf(1.0f + __builtin_amdgcn_exp2f(pre * e_k)),
                 a_mul, a_add);
        const float fv = dpp_bcast<DPP_B1>(act);
        const float gv = dpp_bcast<DPP_B2>(act);
        const float ov = dpp_bcast<DPP_B3>(act);
        c = fmaf(fv, c, act * gv);            // valid on s==0 (act = i-gate)
        const float r2 =
            __builtin_amdgcn_rcpf(1.0f + __builtin_amdgcn_exp2f(c * (-2.0f * LOG2E)));
        const float h = ov * fmaf(2.0f, r2, -1.0f);
        if (s == 0) *(wr_p + ofs) = (_Float16)h;
        __syncthreads();
    };

    for (int w = 0; w < TT / NS; ++w) {
        const int t0 = w * NS;
        if (w == 0) {
            if (tid < 48) ((uint32_t*)hist)[tid] = 0u;  // row 0 = h(-1) = 0
        } else {
            flush(t0 - NS);                              // old xs + rows 1..512
            if (tid < 48)                                // row 512 -> row 0
                ((uint32_t*)hist)[tid] = ((const uint32_t*)(hist + NS * ROWP))[tid];
        }
        __syncthreads();
        for (int i = tid; i < NS; i += TH) xs[i] = x[(t0 + i) * BB + b];
        __syncthreads();

        rd_p = hist + 24 * s;
        wr_p = hist + ROWP + j;
        for (int tt = 0; tt < NS; tt += 8) {
            const float4 xq0 = *(const float4*)(xs + tt);      // broadcast
            const float4 xq1 = *(const float4*)(xs + tt + 4);  // prefetched
            step(xq0.x, 0 * ROWP);
            step(xq0.y, 1 * ROWP);
            step(xq0.z, 2 * ROWP);
            step(xq0.w, 3 * ROWP);
            step(xq1.x, 4 * ROWP);
            step(xq1.y, 5 * ROWP);
            step(xq1.z, 6 * ROWP);
            step(xq1.w, 7 * ROWP);
            rd_p += 8 * ROWP;
            wr_p += 8 * ROWP;
        }
    }
    flush(TT - NS);   // last window (loop ended with a barrier)
}

extern "C" void kernel_launch(void* const* d_in, const int* in_sizes, int n_in,
                              void* d_out, int out_size, void* d_ws, size_t ws_size,
                              hipStream_t stream) {
    const float* x    = (const float*)d_in[0];
    const float* w_ih = (const float*)d_in[1];
    const float* w_hh = (const float*)d_in[2];
    const float* b_ih = (const float*)d_in[3];
    const float* b_hh = (const float*)d_in[4];
    const float* fc_w = (const float*)d_in[5];
    const float* fc_b = (const float*)d_in[6];
    float* out = (float*)d_out;

    lstm_kernel<<<dim3(BB), dim3(TH), 0, stream>>>(x, w_ih, w_hh, b_ih, b_hh,
                                                   fc_w, fc_b, out);
}